// Round 4
// baseline (422.557 us; speedup 1.0000x reference)
//
#include <hip/hip_runtime.h>
#include <cmath>

#define EPSF 1e-5f

// ---------------------------------------------------------------------------
// ws float layout:
//   XDT  = ws               : float [81][B]      transposed downscaled input
//   W2F  = ws + 81*B        : float4[15][7][45]  folded stage-2 conv weights (expert innermost)
//   B2F  = W2F + 18900      : float [15][45]     folded stage-2 bias
//   FC2  = W2F + 19576      : float4[2][15][45]  fcw2 re-laid out (expert innermost)
//   FCB2 = FC2 + 5400       : float [2][45]
//   W1F  = FCB2 + 90        : float [20][9]      folded stage-1 conv weights
//   B1F  = W1F + 180        : float [20]
// ---------------------------------------------------------------------------

__global__ __launch_bounds__(256) void setup_tables(
    const float* __restrict__ w1, const float* __restrict__ b1,
    const float* __restrict__ g1, const float* __restrict__ be1,
    const float* __restrict__ m1, const float* __restrict__ v1,
    const float* __restrict__ w2, const float* __restrict__ b2,
    const float* __restrict__ g2, const float* __restrict__ be2,
    const float* __restrict__ m2, const float* __restrict__ v2,
    const float* __restrict__ fcw2, const float* __restrict__ fcb2,
    float* __restrict__ ws, int B)
{
  const int t  = blockIdx.x * blockDim.x + threadIdx.x;
  const int nt = gridDim.x * blockDim.x;
  float* W2F  = ws + (size_t)81 * B;
  float* B2F  = W2F + 18900;
  float* FC2  = W2F + 19576;
  float* FCB2 = FC2 + 5400;
  float* W1F  = FCB2 + 90;
  float* B1F  = W1F + 180;

  for (int idx = t; idx < 18900; idx += nt) {
    int kk = idx & 3, rest = idx >> 2;
    int e = rest % 45, ok4 = rest / 45;
    int k4 = ok4 % 7, o = ok4 / 7;
    int k = k4 * 4 + kk;
    float s = g2[e*15+o] / sqrtf(v2[e*15+o] + EPSF);
    W2F[idx] = (k < 25) ? w2[(e*15+o)*25 + k] * s : 0.0f;
  }
  for (int idx = t; idx < 675; idx += nt) {
    int e = idx % 45, o = idx / 45;
    float s = g2[e*15+o] / sqrtf(v2[e*15+o] + EPSF);
    B2F[idx] = b2[e*15+o]*s + be2[e*15+o] - m2[e*15+o]*s;
  }
  for (int idx = t; idx < 5400; idx += nt) {
    int kk = idx & 3, rest = idx >> 2;
    int e = rest % 45, t2 = rest / 45;
    int f4 = t2 % 15, oo = t2 / 15;
    FC2[idx] = fcw2[(e*2+oo)*60 + f4*4 + kk];
  }
  for (int idx = t; idx < 90; idx += nt) {
    int e = idx % 45, oo = idx / 45;
    FCB2[idx] = fcb2[e*2+oo];
  }
  for (int idx = t; idx < 180; idx += nt) {
    int ch = idx / 9;
    float s = g1[ch] / sqrtf(v1[ch] + EPSF);
    W1F[idx] = w1[idx] * s;
  }
  for (int idx = t; idx < 20; idx += nt) {
    float s = g1[idx] / sqrtf(v1[idx] + EPSF);
    B1F[idx] = b1[idx]*s + be1[idx] - m1[idx]*s;
  }
}

// ---------------------------------------------------------------------------
// Downscale: thread t -> sample b = t/27, j = t%27 (r = j/3, trip = j%3).
// Reads: in-wave line reuse (a wave covers ~2.4 samples fully).
// Writes: TRANSPOSED xd_t[k][b] (k-plane stride B) - scattered dwords, L2 absorbs.
// 27k waves -> 27 waves/SIMD of TLP: latency fully hidden, bandwidth-bound.
// ---------------------------------------------------------------------------
__global__ __launch_bounds__(256) void downscale_k(
    const float* __restrict__ x, float* __restrict__ ws, int B)
{
  int t = blockIdx.x * blockDim.x + threadIdx.x;
  if (t >= B * 27) return;
  int j = t % 27;
  int b = t / 27;
  int trip = j % 3;
  int r    = j / 3;
  const float* xb = x + (size_t)b * 784;
  float s0 = 0.f, s1 = 0.f, s2 = 0.f;
  #pragma unroll
  for (int dr = 0; dr < 3; dr++) {
    const float* row = xb + (3*r + dr) * 28;
    const float4* rv = reinterpret_cast<const float4*>(row) + 2*trip; // 16B aligned
    float4 A = rv[0], Bv = rv[1], Cv = rv[2];
    if (trip == 0)      { s0 += A.x+A.y+A.z;  s1 += A.w+Bv.x+Bv.y;  s2 += Bv.z+Bv.w+Cv.x; }
    else if (trip == 1) { s0 += A.y+A.z+A.w;  s1 += Bv.x+Bv.y+Bv.z; s2 += Bv.w+Cv.x+Cv.y; }
    else                { s0 += A.z+A.w+Bv.x; s1 += Bv.y+Bv.z+Bv.w; s2 += Cv.x+Cv.y+Cv.z; }
  }
  const int k0 = r * 9 + 3 * trip;
  ws[(size_t)(k0+0) * B + b] = s0 * (1.0f/9.0f);
  ws[(size_t)(k0+1) * B + b] = s1 * (1.0f/9.0f);
  ws[(size_t)(k0+2) * B + b] = s2 * (1.0f/9.0f);
}

// component access into float4 array with compile-time index (after unroll)
#define GETC(arr, k) ((k)%4==0 ? arr[(k)/4].x : (k)%4==1 ? arr[(k)/4].y : \
                      (k)%4==2 ? arr[(k)/4].z : arr[(k)/4].w)

// ---------------------------------------------------------------------------
// Main: 1 thread = 1 sample. xd loaded via 81 independent COALESCED loads
// (lane=b varies fastest in xd_t[k][b]). Everything else in registers.
// ---------------------------------------------------------------------------
__global__ __launch_bounds__(64, 1) void main_k(
    const float* __restrict__ ws,
    const float* __restrict__ fcw1, const float* __restrict__ fcb1,
    float* __restrict__ out, int B)
{
  const int b = blockIdx.x * 64 + threadIdx.x;
  if (b >= B) return;

  const float* W2F  = ws + (size_t)81 * B;
  const float* B2F  = W2F + 18900;
  const float* FC2  = W2F + 19576;
  const float* FCB2 = FC2 + 5400;
  const float* W1F  = FCB2 + 90;
  const float* B1F  = W1F + 180;

  // ---- 81 coalesced, independent loads ----
  float xd[81];
  {
    const float* p = ws + b;
    #pragma unroll
    for (int k = 0; k < 81; k++) xd[k] = p[(size_t)k * B];
  }

  // ---- stage 1: 3x3 conv (BN folded) -> relu -> 2x2 maxpool -> fc1 ----
  float logits[10];
  #pragma unroll
  for (int c = 0; c < 10; c++) logits[c] = fcb1[c];

  #pragma unroll 1
  for (int ch = 0; ch < 20; ch++) {
    float w[9];
    #pragma unroll
    for (int k = 0; k < 9; k++) w[k] = W1F[ch*9 + k];
    float bb = B1F[ch];
    float feat[9];
    #pragma unroll
    for (int pr = 0; pr < 3; pr++) {
      #pragma unroll
      for (int pc = 0; pc < 3; pc++) {
        float c00 = bb, c01 = bb, c10 = bb, c11 = bb;
        #pragma unroll
        for (int dr = 0; dr < 3; dr++) {
          #pragma unroll
          for (int dc = 0; dc < 3; dc++) {
            float wk = w[dr*3 + dc];
            c00 = fmaf(xd[(2*pr+0+dr)*9 + 2*pc+0+dc], wk, c00);
            c01 = fmaf(xd[(2*pr+0+dr)*9 + 2*pc+1+dc], wk, c01);
            c10 = fmaf(xd[(2*pr+1+dr)*9 + 2*pc+0+dc], wk, c10);
            c11 = fmaf(xd[(2*pr+1+dr)*9 + 2*pc+1+dc], wk, c11);
          }
        }
        feat[pr*3+pc] = fmaxf(fmaxf(fmaxf(c00, c01), fmaxf(c10, c11)), 0.0f);
      }
    }
    #pragma unroll
    for (int c = 0; c < 10; c++) {
      float acc = logits[c];
      #pragma unroll
      for (int p = 0; p < 9; p++)
        acc = fmaf(feat[p], fcw1[c*180 + ch*9 + p], acc);
      logits[c] = acc;
    }
  }

  // ---- top-2 (stable-argsort tie semantics: later index wins on tie) ----
  int i1 = 0; float v1m = logits[0];
  #pragma unroll
  for (int c = 1; c < 10; c++) { if (logits[c] >= v1m) { v1m = logits[c]; i1 = c; } }
  int i2 = 0; float v2m = -3.0e38f;
  #pragma unroll
  for (int c = 0; c < 10; c++) { if (c != i1 && logits[c] >= v2m) { v2m = logits[c]; i2 = c; } }
  int idx0 = i1 < i2 ? i1 : i2;
  int idx1 = i1 < i2 ? i2 : i1;
  int eid  = 8*idx0 - (idx0*(idx0-1))/2 + idx1 - 1;   // PAIR_TABLE[idx0][idx1]

  float mx = v1m;
  float sume = 0.0f;
  #pragma unroll
  for (int c = 0; c < 10; c++) sume += expf(logits[c] - mx);
  bool use1 = (-logf(sume)) > 0.3f;

  // ---- stage 2: expert 5x5 conv (BN folded) -> relu -> 2x2 pool -> fc2 ----
  const float4* W2F4 = reinterpret_cast<const float4*>(W2F);
  const float4* FC24 = reinterpret_cast<const float4*>(FC2);

  float s2a = FCB2[eid], s2b = FCB2[45 + eid];

  float4 wv[7], fa, fb; float bias;
  #pragma unroll
  for (int k4 = 0; k4 < 7; k4++) wv[k4] = W2F4[k4*45 + eid];
  bias = B2F[eid];
  fa = FC24[eid];
  fb = FC24[15*45 + eid];

  #pragma unroll 1
  for (int o = 0; o < 15; o++) {
    float4 nwv[7], nfa, nfb; float nbias;
    if (o < 14) {   // prefetch next channel; hidden under the 400 FMAs below
      #pragma unroll
      for (int k4 = 0; k4 < 7; k4++) nwv[k4] = W2F4[((o+1)*7 + k4)*45 + eid];
      nbias = B2F[(o+1)*45 + eid];
      nfa = FC24[(o+1)*45 + eid];
      nfb = FC24[(15 + o+1)*45 + eid];
    }
    float feat0 = 0.f, feat1 = 0.f, feat2 = 0.f, feat3 = 0.f;
    #pragma unroll
    for (int ph = 0; ph < 2; ph++) {
      #pragma unroll
      for (int pw = 0; pw < 2; pw++) {
        float c00 = bias, c01 = bias, c10 = bias, c11 = bias;
        #pragma unroll
        for (int i = 0; i < 5; i++) {
          #pragma unroll
          for (int j = 0; j < 5; j++) {
            float wk = GETC(wv, i*5 + j);
            c00 = fmaf(xd[(2*ph+0+i)*9 + 2*pw+0+j], wk, c00);
            c01 = fmaf(xd[(2*ph+0+i)*9 + 2*pw+1+j], wk, c01);
            c10 = fmaf(xd[(2*ph+1+i)*9 + 2*pw+0+j], wk, c10);
            c11 = fmaf(xd[(2*ph+1+i)*9 + 2*pw+1+j], wk, c11);
          }
        }
        float f = fmaxf(fmaxf(fmaxf(c00, c01), fmaxf(c10, c11)), 0.0f);
        if (ph == 0 && pw == 0) feat0 = f;
        else if (ph == 0)       feat1 = f;
        else if (pw == 0)       feat2 = f;
        else                    feat3 = f;
      }
    }
    s2a = fmaf(feat0, fa.x, fmaf(feat1, fa.y, fmaf(feat2, fa.z, fmaf(feat3, fa.w, s2a))));
    s2b = fmaf(feat0, fb.x, fmaf(feat1, fb.y, fmaf(feat2, fb.z, fmaf(feat3, fb.w, s2b))));
    if (o < 14) {
      #pragma unroll
      for (int k4 = 0; k4 < 7; k4++) wv[k4] = nwv[k4];
      bias = nbias; fa = nfa; fb = nfb;
    }
  }

  // ---- scatter + log_softmax ----
  float o10[10];
  #pragma unroll
  for (int c = 0; c < 10; c++) {
    float v = -100.0f;
    v = (c == idx0) ? s2a : v;
    v = (c == idx1) ? s2b : v;
    o10[c] = use1 ? logits[c] : v;
  }
  float m2x = o10[0];
  #pragma unroll
  for (int c = 1; c < 10; c++) m2x = fmaxf(m2x, o10[c]);
  float se2 = 0.0f;
  #pragma unroll
  for (int c = 0; c < 10; c++) se2 += expf(o10[c] - m2x);
  float lse2 = m2x + logf(se2);

  size_t base = (size_t)b * 10;
  #pragma unroll
  for (int c = 0; c < 10; c++) out[base + c] = logits[c];
  #pragma unroll
  for (int c = 0; c < 10; c++) out[(size_t)B*10 + base + c] = o10[c] - lse2;
}

extern "C" void kernel_launch(void* const* d_in, const int* in_sizes, int n_in,
                              void* d_out, int out_size, void* d_ws, size_t ws_size,
                              hipStream_t stream) {
  const float* x    = (const float*)d_in[0];
  const float* w1   = (const float*)d_in[1];
  const float* b1   = (const float*)d_in[2];
  const float* g1   = (const float*)d_in[3];
  const float* be1  = (const float*)d_in[4];
  const float* m1   = (const float*)d_in[5];
  const float* v1   = (const float*)d_in[6];
  const float* fcw1 = (const float*)d_in[7];
  const float* fcb1 = (const float*)d_in[8];
  const float* w2   = (const float*)d_in[9];
  const float* b2   = (const float*)d_in[10];
  const float* g2   = (const float*)d_in[11];
  const float* be2  = (const float*)d_in[12];
  const float* m2   = (const float*)d_in[13];
  const float* v2   = (const float*)d_in[14];
  const float* fcw2 = (const float*)d_in[15];
  const float* fcb2 = (const float*)d_in[16];
  float* out = (float*)d_out;
  float* ws  = (float*)d_ws;
  const int B = in_sizes[0] / 784;

  setup_tables<<<80, 256, 0, stream>>>(w1, b1, g1, be1, m1, v1,
                                       w2, b2, g2, be2, m2, v2, fcw2, fcb2, ws, B);
  const int nds = B * 27;
  downscale_k<<<(nds + 255)/256, 256, 0, stream>>>(x, ws, B);
  main_k<<<(B + 63)/64, 64, 0, stream>>>(ws, fcw1, fcb1, out, B);
}

// Round 5
// 387.319 us; speedup vs baseline: 1.0910x; 1.0910x over previous
//
#include <hip/hip_runtime.h>
#include <cmath>

#define EPSF 1e-5f

// ---------------------------------------------------------------------------
// ws float layout:
//   XDT  = ws               : float [81][B]      transposed downscaled input
//   W2F  = ws + 81*B        : float4[16][7][45]  folded stage-2 conv weights,
//                             channel-padded to 16 (ch15 = 0), expert innermost
//   B2F  = W2F + 20160      : float [16][45]
//   FC2  = W2F + 20880      : float4[2][16][45]  fcw2 re-laid out (ch-padded)
//   FCB2 = W2F + 26640      : float [2][45]
//   W1F  = W2F + 26730      : float [20][9]
//   B1F  = W2F + 26910      : float [20]
// total tables = 26930 floats (~108 KB); XDT = 21.2 MB
// ---------------------------------------------------------------------------

__global__ __launch_bounds__(256) void setup_tables(
    const float* __restrict__ w1, const float* __restrict__ b1,
    const float* __restrict__ g1, const float* __restrict__ be1,
    const float* __restrict__ m1, const float* __restrict__ v1,
    const float* __restrict__ w2, const float* __restrict__ b2,
    const float* __restrict__ g2, const float* __restrict__ be2,
    const float* __restrict__ m2, const float* __restrict__ v2,
    const float* __restrict__ fcw2, const float* __restrict__ fcb2,
    float* __restrict__ ws, int B)
{
  const int t  = blockIdx.x * blockDim.x + threadIdx.x;
  const int nt = gridDim.x * blockDim.x;
  float* W2F  = ws + (size_t)81 * B;
  float* B2F  = W2F + 20160;
  float* FC2  = W2F + 20880;
  float* FCB2 = W2F + 26640;
  float* W1F  = W2F + 26730;
  float* B1F  = W2F + 26910;

  // W2F: idx = ((o*7+k4)*45+e)*4+kk ; o in 0..15 (15 => zero pad)
  for (int idx = t; idx < 20160; idx += nt) {
    int kk = idx & 3, rest = idx >> 2;
    int e = rest % 45, ok4 = rest / 45;
    int k4 = ok4 % 7, o = ok4 / 7;
    int k = k4 * 4 + kk;
    float val = 0.0f;
    if (o < 15 && k < 25) {
      float s = g2[e*15+o] / sqrtf(v2[e*15+o] + EPSF);
      val = w2[(e*15+o)*25 + k] * s;
    }
    W2F[idx] = val;
  }
  for (int idx = t; idx < 720; idx += nt) {
    int e = idx % 45, o = idx / 45;
    float val = 0.0f;
    if (o < 15) {
      float s = g2[e*15+o] / sqrtf(v2[e*15+o] + EPSF);
      val = b2[e*15+o]*s + be2[e*15+o] - m2[e*15+o]*s;
    }
    B2F[idx] = val;
  }
  // FC2: idx = ((oo*16+o)*45+e)*4+kk  (feat index = o*4+kk; o==15 => 0)
  for (int idx = t; idx < 5760; idx += nt) {
    int kk = idx & 3, rest = idx >> 2;
    int e = rest % 45, t2 = rest / 45;
    int o = t2 % 16, oo = t2 / 16;
    FC2[idx] = (o < 15) ? fcw2[(e*2+oo)*60 + o*4 + kk] : 0.0f;
  }
  for (int idx = t; idx < 90; idx += nt) {
    int e = idx % 45, oo = idx / 45;
    FCB2[idx] = fcb2[e*2+oo];
  }
  for (int idx = t; idx < 180; idx += nt) {
    int ch = idx / 9;
    float s = g1[ch] / sqrtf(v1[ch] + EPSF);
    W1F[idx] = w1[idx] * s;
  }
  for (int idx = t; idx < 20; idx += nt) {
    float s = g1[idx] / sqrtf(v1[idx] + EPSF);
    B1F[idx] = b1[idx]*s + be1[idx] - m1[idx]*s;
  }
}

// ---------------------------------------------------------------------------
// Downscale + transpose through LDS.
// Block = 256 threads = 64 samples. Phase 1: round-1 read pattern (in-wave
// line reuse) into sxd[s*81+k]; stride 81, gcd(81,32)=1 -> <=2-way conflicts
// (free). Phase 2: coalesced writes ws[k*B + b0+s] (256B contiguous / wave).
// 1024 blocks x 4 waves -> plenty TLP; pure bandwidth kernel.
// ---------------------------------------------------------------------------
__global__ __launch_bounds__(256) void downscale_t(
    const float* __restrict__ x, float* __restrict__ ws, int B)
{
  __shared__ float sxd[64 * 81];
  const int tid = threadIdx.x;
  const int b0  = blockIdx.x * 64;

  #pragma unroll 1
  for (int idx = tid; idx < 1728; idx += 256) {
    int s = idx / 27, j = idx % 27;
    int r = j / 3, trip = j % 3;
    const float* xb = x + (size_t)(b0 + s) * 784;
    float s0 = 0.f, s1 = 0.f, s2 = 0.f;
    #pragma unroll
    for (int dr = 0; dr < 3; dr++) {
      const float* row = xb + (3*r + dr) * 28;
      const float4* rv = reinterpret_cast<const float4*>(row) + 2*trip; // 16B aligned
      float4 A = rv[0], Bv = rv[1], Cv = rv[2];
      if (trip == 0)      { s0 += A.x+A.y+A.z;  s1 += A.w+Bv.x+Bv.y;  s2 += Bv.z+Bv.w+Cv.x; }
      else if (trip == 1) { s0 += A.y+A.z+A.w;  s1 += Bv.x+Bv.y+Bv.z; s2 += Bv.w+Cv.x+Cv.y; }
      else                { s0 += A.z+A.w+Bv.x; s1 += Bv.y+Bv.z+Bv.w; s2 += Cv.x+Cv.y+Cv.z; }
    }
    float* q = &sxd[s*81 + r*9 + 3*trip];
    q[0] = s0 * (1.0f/9.0f); q[1] = s1 * (1.0f/9.0f); q[2] = s2 * (1.0f/9.0f);
  }
  __syncthreads();

  #pragma unroll 1
  for (int idx = tid; idx < 5184; idx += 256) {
    int k = idx >> 6, s = idx & 63;
    ws[(size_t)k * B + (b0 + s)] = sxd[s*81 + k];
  }
}

// ---------------------------------------------------------------------------
// Main: 2 lanes per sample (sub = g&1). 2048 waves -> 2 waves/SIMD.
// Stage-1 conv split by channel parity; fc1 via dual partial sums P/Q with
// wave-uniform (scalar) weights + one shfl_xor butterfly. Stage-2 split over
// 16 zero-padded channels; partial s2a/s2b butterfly-reduced.
// ---------------------------------------------------------------------------
__global__ __launch_bounds__(256, 2) void main_dual(
    const float* __restrict__ ws,
    const float* __restrict__ fcw1, const float* __restrict__ fcb1,
    float* __restrict__ out, int B)
{
  const int g   = blockIdx.x * 256 + threadIdx.x;
  const int b   = g >> 1;
  const int sub = g & 1;

  const float* W2F  = ws + (size_t)81 * B;
  const float* B2F  = W2F + 20160;
  const float* FC2  = W2F + 20880;
  const float* FCB2 = W2F + 26640;
  const float* W1F  = W2F + 26730;
  const float* B1F  = W2F + 26910;

  // ---- 81 coalesced loads (lane pairs broadcast; 128B span / instr) ----
  float xd[81];
  {
    const float* p = ws + b;
    #pragma unroll
    for (int k = 0; k < 81; k++) xd[k] = p[(size_t)k * B];
  }

  // ---- stage 1: conv channels 2*s1+sub; fc1 as P (even rows) / Q (odd) ----
  float P[10], Q[10];
  #pragma unroll
  for (int c = 0; c < 10; c++) { P[c] = 0.0f; Q[c] = 0.0f; }

  #pragma unroll 1
  for (int s1 = 0; s1 < 10; s1++) {
    const int ch = 2*s1 + sub;
    float w[9];
    #pragma unroll
    for (int k = 0; k < 9; k++) w[k] = W1F[ch*9 + k];
    float bb = B1F[ch];
    float feat[9];
    #pragma unroll
    for (int pr = 0; pr < 3; pr++) {
      #pragma unroll
      for (int pc = 0; pc < 3; pc++) {
        float c00 = bb, c01 = bb, c10 = bb, c11 = bb;
        #pragma unroll
        for (int dr = 0; dr < 3; dr++) {
          #pragma unroll
          for (int dc = 0; dc < 3; dc++) {
            float wk = w[dr*3 + dc];
            c00 = fmaf(xd[(2*pr+0+dr)*9 + 2*pc+0+dc], wk, c00);
            c01 = fmaf(xd[(2*pr+0+dr)*9 + 2*pc+1+dc], wk, c01);
            c10 = fmaf(xd[(2*pr+1+dr)*9 + 2*pc+0+dc], wk, c10);
            c11 = fmaf(xd[(2*pr+1+dr)*9 + 2*pc+1+dc], wk, c11);
          }
        }
        feat[pr*3+pc] = fmaxf(fmaxf(fmaxf(c00, c01), fmaxf(c10, c11)), 0.0f);
      }
    }
    // accumulate against BOTH weight rows (uniform addresses -> scalar loads)
    #pragma unroll
    for (int c = 0; c < 10; c++) {
      float accP = P[c], accQ = Q[c];
      #pragma unroll
      for (int pp = 0; pp < 9; pp++) {
        accP = fmaf(feat[pp], fcw1[c*180 + (2*s1+0)*9 + pp], accP);
        accQ = fmaf(feat[pp], fcw1[c*180 + (2*s1+1)*9 + pp], accQ);
      }
      P[c] = accP; Q[c] = accQ;
    }
  }

  float logits[10];
  #pragma unroll
  for (int c = 0; c < 10; c++) {
    float sel = sub ? Q[c] : P[c];          // my true contribution
    logits[c] = sel + __shfl_xor(sel, 1) + fcb1[c];
  }

  // ---- top-2 (identical on both lanes: FP add is commutative) ----
  int i1 = 0; float v1m = logits[0];
  #pragma unroll
  for (int c = 1; c < 10; c++) { if (logits[c] >= v1m) { v1m = logits[c]; i1 = c; } }
  int i2 = 0; float v2m = -3.0e38f;
  #pragma unroll
  for (int c = 0; c < 10; c++) { if (c != i1 && logits[c] >= v2m) { v2m = logits[c]; i2 = c; } }
  int idx0 = i1 < i2 ? i1 : i2;
  int idx1 = i1 < i2 ? i2 : i1;
  int eid  = 8*idx0 - (idx0*(idx0-1))/2 + idx1 - 1;   // PAIR_TABLE[idx0][idx1]

  float mx = v1m;
  float sume = 0.0f;
  #pragma unroll
  for (int c = 0; c < 10; c++) sume += expf(logits[c] - mx);
  bool use1 = (-logf(sume)) > 0.3f;

  // ---- stage 2: channels o = 2j+sub, j=0..7 (16 padded) ----
  const float4* W2F4 = reinterpret_cast<const float4*>(W2F);
  const float4* FC24 = reinterpret_cast<const float4*>(FC2);

  float s2a = 0.0f, s2b = 0.0f;
  float4 wv[7], fa, fb; float bias;
  {
    const int o = sub;
    #pragma unroll
    for (int k4 = 0; k4 < 7; k4++) wv[k4] = W2F4[(o*7 + k4)*45 + eid];
    bias = B2F[o*45 + eid];
    fa = FC24[(0*16 + o)*45 + eid];
    fb = FC24[(1*16 + o)*45 + eid];
  }

  #pragma unroll 1
  for (int j = 0; j < 8; j++) {
    float4 nwv[7], nfa, nfb; float nbias;
    if (j < 7) {   // prefetch next channel; hidden under the 400 FMAs below
      const int o = 2*(j+1) + sub;
      #pragma unroll
      for (int k4 = 0; k4 < 7; k4++) nwv[k4] = W2F4[(o*7 + k4)*45 + eid];
      nbias = B2F[o*45 + eid];
      nfa = FC24[(0*16 + o)*45 + eid];
      nfb = FC24[(1*16 + o)*45 + eid];
    }
    float feats[4];
    #pragma unroll
    for (int ph = 0; ph < 2; ph++) {
      #pragma unroll
      for (int pw = 0; pw < 2; pw++) {
        float c00 = bias, c01 = bias, c10 = bias, c11 = bias;
        #pragma unroll
        for (int i = 0; i < 5; i++) {
          #pragma unroll
          for (int jj = 0; jj < 5; jj++) {
            int k = i*5 + jj;
            float wk = (k%4==0) ? wv[k/4].x : (k%4==1) ? wv[k/4].y :
                       (k%4==2) ? wv[k/4].z : wv[k/4].w;
            c00 = fmaf(xd[(2*ph+0+i)*9 + 2*pw+0+jj], wk, c00);
            c01 = fmaf(xd[(2*ph+0+i)*9 + 2*pw+1+jj], wk, c01);
            c10 = fmaf(xd[(2*ph+1+i)*9 + 2*pw+0+jj], wk, c10);
            c11 = fmaf(xd[(2*ph+1+i)*9 + 2*pw+1+jj], wk, c11);
          }
        }
        feats[ph*2+pw] = fmaxf(fmaxf(fmaxf(c00, c01), fmaxf(c10, c11)), 0.0f);
      }
    }
    s2a = fmaf(feats[0], fa.x, fmaf(feats[1], fa.y, fmaf(feats[2], fa.z, fmaf(feats[3], fa.w, s2a))));
    s2b = fmaf(feats[0], fb.x, fmaf(feats[1], fb.y, fmaf(feats[2], fb.z, fmaf(feats[3], fb.w, s2b))));
    if (j < 7) {
      #pragma unroll
      for (int k4 = 0; k4 < 7; k4++) wv[k4] = nwv[k4];
      bias = nbias; fa = nfa; fb = nfb;
    }
  }
  s2a += __shfl_xor(s2a, 1);
  s2b += __shfl_xor(s2b, 1);
  s2a += FCB2[eid];
  s2b += FCB2[45 + eid];

  // ---- scatter + log_softmax (redundant on both lanes) ----
  float o10[10];
  #pragma unroll
  for (int c = 0; c < 10; c++) {
    float v = -100.0f;
    v = (c == idx0) ? s2a : v;
    v = (c == idx1) ? s2b : v;
    o10[c] = use1 ? logits[c] : v;
  }
  float m2x = o10[0];
  #pragma unroll
  for (int c = 1; c < 10; c++) m2x = fmaxf(m2x, o10[c]);
  float se2 = 0.0f;
  #pragma unroll
  for (int c = 0; c < 10; c++) se2 += expf(o10[c] - m2x);
  float lse2 = m2x + logf(se2);

  size_t base = (size_t)b * 10;
  if (sub == 0) {
    #pragma unroll
    for (int c = 0; c < 10; c++) out[base + c] = logits[c];
  } else {
    #pragma unroll
    for (int c = 0; c < 10; c++) out[(size_t)B*10 + base + c] = o10[c] - lse2;
  }
}

extern "C" void kernel_launch(void* const* d_in, const int* in_sizes, int n_in,
                              void* d_out, int out_size, void* d_ws, size_t ws_size,
                              hipStream_t stream) {
  const float* x    = (const float*)d_in[0];
  const float* w1   = (const float*)d_in[1];
  const float* b1   = (const float*)d_in[2];
  const float* g1   = (const float*)d_in[3];
  const float* be1  = (const float*)d_in[4];
  const float* m1   = (const float*)d_in[5];
  const float* v1   = (const float*)d_in[6];
  const float* fcw1 = (const float*)d_in[7];
  const float* fcb1 = (const float*)d_in[8];
  const float* w2   = (const float*)d_in[9];
  const float* b2   = (const float*)d_in[10];
  const float* g2   = (const float*)d_in[11];
  const float* be2  = (const float*)d_in[12];
  const float* m2   = (const float*)d_in[13];
  const float* v2   = (const float*)d_in[14];
  const float* fcw2 = (const float*)d_in[15];
  const float* fcb2 = (const float*)d_in[16];
  float* out = (float*)d_out;
  float* ws  = (float*)d_ws;
  const int B = in_sizes[0] / 784;

  setup_tables<<<80, 256, 0, stream>>>(w1, b1, g1, be1, m1, v1,
                                       w2, b2, g2, be2, m2, v2, fcw2, fcb2, ws, B);
  downscale_t<<<B/64, 256, 0, stream>>>(x, ws, B);
  main_dual<<<(2*B)/256, 256, 0, stream>>>(ws, fcw1, fcb1, out, B);
}

// Round 6
// 369.911 us; speedup vs baseline: 1.1423x; 1.0471x over previous
//
#include <hip/hip_runtime.h>
#include <cmath>

#define EPSF 1e-5f

// ---------------------------------------------------------------------------
// ws float layout (tables only; xd lives in LDS):
//   W2F  = ws               : float4[16][7][45]  folded stage-2 conv weights,
//                             channel-padded to 16 (ch15 = 0), expert innermost
//   B2F  = ws + 20160       : float [16][45]
//   FC2  = ws + 20880       : float4[2][16][45]  fcw2 re-laid out (ch-padded)
//   FCB2 = ws + 26640       : float [2][45]
//   W1F  = ws + 26730       : float [20][9]
//   B1F  = ws + 26910       : float [20]
// total = 26930 floats (~108 KB)
// ---------------------------------------------------------------------------

__global__ __launch_bounds__(256) void setup_tables(
    const float* __restrict__ w1, const float* __restrict__ b1,
    const float* __restrict__ g1, const float* __restrict__ be1,
    const float* __restrict__ m1, const float* __restrict__ v1,
    const float* __restrict__ w2, const float* __restrict__ b2,
    const float* __restrict__ g2, const float* __restrict__ be2,
    const float* __restrict__ m2, const float* __restrict__ v2,
    const float* __restrict__ fcw2, const float* __restrict__ fcb2,
    float* __restrict__ ws)
{
  const int t  = blockIdx.x * blockDim.x + threadIdx.x;
  const int nt = gridDim.x * blockDim.x;
  float* W2F  = ws;
  float* B2F  = ws + 20160;
  float* FC2  = ws + 20880;
  float* FCB2 = ws + 26640;
  float* W1F  = ws + 26730;
  float* B1F  = ws + 26910;

  // W2F: idx = ((o*7+k4)*45+e)*4+kk ; o in 0..15 (15 => zero pad)
  for (int idx = t; idx < 20160; idx += nt) {
    int kk = idx & 3, rest = idx >> 2;
    int e = rest % 45, ok4 = rest / 45;
    int k4 = ok4 % 7, o = ok4 / 7;
    int k = k4 * 4 + kk;
    float val = 0.0f;
    if (o < 15 && k < 25) {
      float s = g2[e*15+o] / sqrtf(v2[e*15+o] + EPSF);
      val = w2[(e*15+o)*25 + k] * s;
    }
    W2F[idx] = val;
  }
  for (int idx = t; idx < 720; idx += nt) {
    int e = idx % 45, o = idx / 45;
    float val = 0.0f;
    if (o < 15) {
      float s = g2[e*15+o] / sqrtf(v2[e*15+o] + EPSF);
      val = b2[e*15+o]*s + be2[e*15+o] - m2[e*15+o]*s;
    }
    B2F[idx] = val;
  }
  // FC2: idx = ((oo*16+o)*45+e)*4+kk  (feat index = o*4+kk; o==15 => 0)
  for (int idx = t; idx < 5760; idx += nt) {
    int kk = idx & 3, rest = idx >> 2;
    int e = rest % 45, t2 = rest / 45;
    int o = t2 % 16, oo = t2 / 16;
    FC2[idx] = (o < 15) ? fcw2[(e*2+oo)*60 + o*4 + kk] : 0.0f;
  }
  for (int idx = t; idx < 90; idx += nt) {
    int e = idx % 45, oo = idx / 45;
    FCB2[idx] = fcb2[e*2+oo];
  }
  for (int idx = t; idx < 180; idx += nt) {
    int ch = idx / 9;
    float s = g1[ch] / sqrtf(v1[ch] + EPSF);
    W1F[idx] = w1[idx] * s;
  }
  for (int idx = t; idx < 20; idx += nt) {
    float s = g1[idx] / sqrtf(v1[idx] + EPSF);
    B1F[idx] = b1[idx]*s + be1[idx] - m1[idx]*s;
  }
}

// ---------------------------------------------------------------------------
// Fused: 256 threads / 128 samples per block; grid 512 -> 2048 waves
// (2 waves/SIMD). __launch_bounds__(256,2) -> 256-VGPR budget, no spill.
// Phase 1: cooperative downscale of 128 samples into LDS (41.5 KB).
// Phase 2: 2 lanes per sample (sub = tid&1), channel-parity split,
//          shfl_xor butterfly reductions, xd from LDS (stride-81: banks
//          17*s mod 32 all distinct; pair-broadcast is free).
// ---------------------------------------------------------------------------
__global__ __launch_bounds__(256, 2) void fused2(
    const float* __restrict__ x,
    const float* __restrict__ ws,
    const float* __restrict__ fcw1, const float* __restrict__ fcb1,
    float* __restrict__ out, int B)
{
  __shared__ float sxd[128 * 81];
  const int tid = threadIdx.x;
  const int b0  = blockIdx.x * 128;
  const int nvalid = (B - b0 < 128) ? (B - b0) : 128;

  // ---- phase 1: downscale 128 samples (3456 tasks of (s, r, trip)) ----
  #pragma unroll 1
  for (int idx = tid; idx < 3456; idx += 256) {
    int s = idx / 27, j = idx % 27;
    if (s < nvalid) {
      int r = j / 3, trip = j % 3;
      const float* xb = x + (size_t)(b0 + s) * 784;
      float s0 = 0.f, s1 = 0.f, s2 = 0.f;
      #pragma unroll
      for (int dr = 0; dr < 3; dr++) {
        const float* row = xb + (3*r + dr) * 28;
        const float4* rv = reinterpret_cast<const float4*>(row) + 2*trip; // 16B aligned
        float4 A = rv[0], Bv = rv[1], Cv = rv[2];
        if (trip == 0)      { s0 += A.x+A.y+A.z;  s1 += A.w+Bv.x+Bv.y;  s2 += Bv.z+Bv.w+Cv.x; }
        else if (trip == 1) { s0 += A.y+A.z+A.w;  s1 += Bv.x+Bv.y+Bv.z; s2 += Bv.w+Cv.x+Cv.y; }
        else                { s0 += A.z+A.w+Bv.x; s1 += Bv.y+Bv.z+Bv.w; s2 += Cv.x+Cv.y+Cv.z; }
      }
      float* q = &sxd[s*81 + r*9 + 3*trip];
      q[0] = s0 * (1.0f/9.0f); q[1] = s1 * (1.0f/9.0f); q[2] = s2 * (1.0f/9.0f);
    }
  }
  __syncthreads();

  const int s_local = tid >> 1;
  const int sub     = tid & 1;
  const int b       = b0 + s_local;
  if (s_local >= nvalid) return;

  const float* W2F  = ws;
  const float* B2F  = ws + 20160;
  const float* FC2  = ws + 20880;
  const float* FCB2 = ws + 26640;
  const float* W1F  = ws + 26730;
  const float* B1F  = ws + 26910;

  // ---- xd from LDS ----
  float xd[81];
  {
    const float* p = &sxd[s_local * 81];
    #pragma unroll
    for (int k = 0; k < 81; k++) xd[k] = p[k];
  }

  // ---- stage 1: conv channels 2*s1+sub; fc1 as P (even rows) / Q (odd) ----
  float P[10], Q[10];
  #pragma unroll
  for (int c = 0; c < 10; c++) { P[c] = 0.0f; Q[c] = 0.0f; }

  #pragma unroll 1
  for (int s1 = 0; s1 < 10; s1++) {
    const int ch = 2*s1 + sub;
    float w[9];
    #pragma unroll
    for (int k = 0; k < 9; k++) w[k] = W1F[ch*9 + k];
    float bb = B1F[ch];
    float feat[9];
    #pragma unroll
    for (int pr = 0; pr < 3; pr++) {
      #pragma unroll
      for (int pc = 0; pc < 3; pc++) {
        float c00 = bb, c01 = bb, c10 = bb, c11 = bb;
        #pragma unroll
        for (int dr = 0; dr < 3; dr++) {
          #pragma unroll
          for (int dc = 0; dc < 3; dc++) {
            float wk = w[dr*3 + dc];
            c00 = fmaf(xd[(2*pr+0+dr)*9 + 2*pc+0+dc], wk, c00);
            c01 = fmaf(xd[(2*pr+0+dr)*9 + 2*pc+1+dc], wk, c01);
            c10 = fmaf(xd[(2*pr+1+dr)*9 + 2*pc+0+dc], wk, c10);
            c11 = fmaf(xd[(2*pr+1+dr)*9 + 2*pc+1+dc], wk, c11);
          }
        }
        feat[pr*3+pc] = fmaxf(fmaxf(fmaxf(c00, c01), fmaxf(c10, c11)), 0.0f);
      }
    }
    // accumulate against BOTH weight rows (uniform addresses -> scalar loads)
    #pragma unroll
    for (int c = 0; c < 10; c++) {
      float accP = P[c], accQ = Q[c];
      #pragma unroll
      for (int pp = 0; pp < 9; pp++) {
        accP = fmaf(feat[pp], fcw1[c*180 + (2*s1+0)*9 + pp], accP);
        accQ = fmaf(feat[pp], fcw1[c*180 + (2*s1+1)*9 + pp], accQ);
      }
      P[c] = accP; Q[c] = accQ;
    }
  }

  float logits[10];
  #pragma unroll
  for (int c = 0; c < 10; c++) {
    float sel = sub ? Q[c] : P[c];          // my true contribution
    logits[c] = sel + __shfl_xor(sel, 1) + fcb1[c];
  }

  // ---- top-2 (identical on both lanes: FP add is commutative) ----
  int i1 = 0; float v1m = logits[0];
  #pragma unroll
  for (int c = 1; c < 10; c++) { if (logits[c] >= v1m) { v1m = logits[c]; i1 = c; } }
  int i2 = 0; float v2m = -3.0e38f;
  #pragma unroll
  for (int c = 0; c < 10; c++) { if (c != i1 && logits[c] >= v2m) { v2m = logits[c]; i2 = c; } }
  int idx0 = i1 < i2 ? i1 : i2;
  int idx1 = i1 < i2 ? i2 : i1;
  int eid  = 8*idx0 - (idx0*(idx0-1))/2 + idx1 - 1;   // PAIR_TABLE[idx0][idx1]

  float mx = v1m;
  float sume = 0.0f;
  #pragma unroll
  for (int c = 0; c < 10; c++) sume += expf(logits[c] - mx);
  bool use1 = (-logf(sume)) > 0.3f;

  // ---- stage 2: channels o = 2j+sub, j=0..7 (16 zero-padded) ----
  const float4* W2F4 = reinterpret_cast<const float4*>(W2F);
  const float4* FC24 = reinterpret_cast<const float4*>(FC2);

  float s2a = 0.0f, s2b = 0.0f;
  float4 wv[7], fa, fb; float bias;
  {
    const int o = sub;
    #pragma unroll
    for (int k4 = 0; k4 < 7; k4++) wv[k4] = W2F4[(o*7 + k4)*45 + eid];
    bias = B2F[o*45 + eid];
    fa = FC24[(0*16 + o)*45 + eid];
    fb = FC24[(1*16 + o)*45 + eid];
  }

  #pragma unroll 1
  for (int j = 0; j < 8; j++) {
    float4 nwv[7], nfa, nfb; float nbias;
    if (j < 7) {   // prefetch next channel; hidden under the 400 FMAs below
      const int o = 2*(j+1) + sub;
      #pragma unroll
      for (int k4 = 0; k4 < 7; k4++) nwv[k4] = W2F4[(o*7 + k4)*45 + eid];
      nbias = B2F[o*45 + eid];
      nfa = FC24[(0*16 + o)*45 + eid];
      nfb = FC24[(1*16 + o)*45 + eid];
    }
    float feats[4];
    #pragma unroll
    for (int ph = 0; ph < 2; ph++) {
      #pragma unroll
      for (int pw = 0; pw < 2; pw++) {
        float c00 = bias, c01 = bias, c10 = bias, c11 = bias;
        #pragma unroll
        for (int i = 0; i < 5; i++) {
          #pragma unroll
          for (int jj = 0; jj < 5; jj++) {
            int k = i*5 + jj;
            float wk = (k%4==0) ? wv[k/4].x : (k%4==1) ? wv[k/4].y :
                       (k%4==2) ? wv[k/4].z : wv[k/4].w;
            c00 = fmaf(xd[(2*ph+0+i)*9 + 2*pw+0+jj], wk, c00);
            c01 = fmaf(xd[(2*ph+0+i)*9 + 2*pw+1+jj], wk, c01);
            c10 = fmaf(xd[(2*ph+1+i)*9 + 2*pw+0+jj], wk, c10);
            c11 = fmaf(xd[(2*ph+1+i)*9 + 2*pw+1+jj], wk, c11);
          }
        }
        feats[ph*2+pw] = fmaxf(fmaxf(fmaxf(c00, c01), fmaxf(c10, c11)), 0.0f);
      }
    }
    s2a = fmaf(feats[0], fa.x, fmaf(feats[1], fa.y, fmaf(feats[2], fa.z, fmaf(feats[3], fa.w, s2a))));
    s2b = fmaf(feats[0], fb.x, fmaf(feats[1], fb.y, fmaf(feats[2], fb.z, fmaf(feats[3], fb.w, s2b))));
    if (j < 7) {
      #pragma unroll
      for (int k4 = 0; k4 < 7; k4++) wv[k4] = nwv[k4];
      bias = nbias; fa = nfa; fb = nfb;
    }
  }
  s2a += __shfl_xor(s2a, 1);
  s2b += __shfl_xor(s2b, 1);
  s2a += FCB2[eid];
  s2b += FCB2[45 + eid];

  // ---- scatter + log_softmax (redundant on both lanes) ----
  float o10[10];
  #pragma unroll
  for (int c = 0; c < 10; c++) {
    float v = -100.0f;
    v = (c == idx0) ? s2a : v;
    v = (c == idx1) ? s2b : v;
    o10[c] = use1 ? logits[c] : v;
  }
  float m2x = o10[0];
  #pragma unroll
  for (int c = 1; c < 10; c++) m2x = fmaxf(m2x, o10[c]);
  float se2 = 0.0f;
  #pragma unroll
  for (int c = 0; c < 10; c++) se2 += expf(o10[c] - m2x);
  float lse2 = m2x + logf(se2);

  size_t base = (size_t)b * 10;
  if (sub == 0) {
    #pragma unroll
    for (int c = 0; c < 10; c++) out[base + c] = logits[c];
  } else {
    #pragma unroll
    for (int c = 0; c < 10; c++) out[(size_t)B*10 + base + c] = o10[c] - lse2;
  }
}

extern "C" void kernel_launch(void* const* d_in, const int* in_sizes, int n_in,
                              void* d_out, int out_size, void* d_ws, size_t ws_size,
                              hipStream_t stream) {
  const float* x    = (const float*)d_in[0];
  const float* w1   = (const float*)d_in[1];
  const float* b1   = (const float*)d_in[2];
  const float* g1   = (const float*)d_in[3];
  const float* be1  = (const float*)d_in[4];
  const float* m1   = (const float*)d_in[5];
  const float* v1   = (const float*)d_in[6];
  const float* fcw1 = (const float*)d_in[7];
  const float* fcb1 = (const float*)d_in[8];
  const float* w2   = (const float*)d_in[9];
  const float* b2   = (const float*)d_in[10];
  const float* g2   = (const float*)d_in[11];
  const float* be2  = (const float*)d_in[12];
  const float* m2   = (const float*)d_in[13];
  const float* v2   = (const float*)d_in[14];
  const float* fcw2 = (const float*)d_in[15];
  const float* fcb2 = (const float*)d_in[16];
  float* out = (float*)d_out;
  float* ws  = (float*)d_ws;
  const int B = in_sizes[0] / 784;

  setup_tables<<<80, 256, 0, stream>>>(w1, b1, g1, be1, m1, v1,
                                       w2, b2, g2, be2, m2, v2, fcw2, fcb2, ws);
  fused2<<<(B + 127)/128, 256, 0, stream>>>(x, ws, fcw1, fcb1, out, B);
}